// Round 1
// baseline (1471.701 us; speedup 1.0000x reference)
//
#include <hip/hip_runtime.h>
#include <hip/hip_bf16.h>

#define B_  2
#define S_  2048
#define D_  2048
#define H_  16
#define HD_ 128
#define FF_ 8192

typedef __bf16 bf16x8 __attribute__((ext_vector_type(8)));
typedef float  f32x4  __attribute__((ext_vector_type(4)));
typedef unsigned short u16;

__device__ __forceinline__ u16 f2bf(float f) {
    union { float f; unsigned u; } c; c.f = f;
    unsigned u = c.u;
    u += 0x7fffu + ((u >> 16) & 1u);   // RNE
    return (u16)(u >> 16);
}

__device__ __forceinline__ void gld16(void* lds, const void* g) {
    __builtin_amdgcn_global_load_lds(
        (const __attribute__((address_space(1))) unsigned int*)g,
        (__attribute__((address_space(3))) unsigned int*)lds,
        16, 0, 0);
}

// ---------------------------------------------------------------- LayerNorm
// one block per row of 2048 fp32; output bf16
__global__ __launch_bounds__(256)
void ln_kernel(const float* __restrict__ x, const float* __restrict__ g,
               const float* __restrict__ bb, u16* __restrict__ out)
{
    int row = blockIdx.x, tid = threadIdx.x;
    const float4* xr = (const float4*)(x + (size_t)row * D_);
    float4 a = xr[tid], c = xr[tid + 256];
    float s  = a.x + a.y + a.z + a.w + c.x + c.y + c.z + c.w;
    float s2 = a.x*a.x + a.y*a.y + a.z*a.z + a.w*a.w
             + c.x*c.x + c.y*c.y + c.z*c.z + c.w*c.w;
    #pragma unroll
    for (int off = 32; off > 0; off >>= 1) {
        s  += __shfl_down(s,  off, 64);
        s2 += __shfl_down(s2, off, 64);
    }
    __shared__ float red[16];
    __shared__ float mr[2];
    int wid = tid >> 6, lane = tid & 63;
    if (lane == 0) { red[wid] = s; red[8 + wid] = s2; }
    __syncthreads();
    if (tid == 0) {
        float ts = red[0] + red[1] + red[2] + red[3];
        float t2 = red[8] + red[9] + red[10] + red[11];
        float mu = ts * (1.0f / D_);
        float var = t2 * (1.0f / D_) - mu * mu;
        mr[0] = mu; mr[1] = rsqrtf(var + 1e-5f);
    }
    __syncthreads();
    float mu = mr[0], rstd = mr[1];
    const float4* gg = (const float4*)g;
    const float4* bv = (const float4*)bb;
    float4 g0 = gg[tid], g1 = gg[tid + 256];
    float4 b0 = bv[tid], b1 = bv[tid + 256];
    u16* orow = out + (size_t)row * D_;
    ushort4 o0, o1;
    o0.x = f2bf((a.x - mu) * rstd * g0.x + b0.x);
    o0.y = f2bf((a.y - mu) * rstd * g0.y + b0.y);
    o0.z = f2bf((a.z - mu) * rstd * g0.z + b0.z);
    o0.w = f2bf((a.w - mu) * rstd * g0.w + b0.w);
    o1.x = f2bf((c.x - mu) * rstd * g1.x + b1.x);
    o1.y = f2bf((c.y - mu) * rstd * g1.y + b1.y);
    o1.z = f2bf((c.z - mu) * rstd * g1.z + b1.z);
    o1.w = f2bf((c.w - mu) * rstd * g1.w + b1.w);
    *(ushort4*)&orow[tid * 4]         = o0;
    *(ushort4*)&orow[(tid + 256) * 4] = o1;
}

// ----------------------------------------------- transpose + fp32->bf16 cast
// W[K][N] fp32 -> WT[N][K] bf16
__global__ __launch_bounds__(256)
void tcvt_kernel(const float* __restrict__ W, u16* __restrict__ WT, int K, int N)
{
    __shared__ float t[32][33];
    int n0 = blockIdx.x << 5, k0 = blockIdx.y << 5;
    int tx = threadIdx.x & 31, ty = threadIdx.x >> 5;
    #pragma unroll
    for (int i = 0; i < 32; i += 8)
        t[ty + i][tx] = W[(size_t)(k0 + ty + i) * N + n0 + tx];
    __syncthreads();
    #pragma unroll
    for (int i = 0; i < 32; i += 8)
        WT[(size_t)(n0 + ty + i) * K + k0 + tx] = f2bf(t[tx][ty + i]);
}

// ---------------------------------------------------------------- GEMM bf16
// C[M,N] = A[M,K](bf16,row) * BT[N,K](bf16,row)^T + bias
// EPI 0: store bf16; 1: GELU, store bf16; 2: +res(fp32), store fp32
template<int EPI>
__global__ __launch_bounds__(256)
void gemm_kernel(const u16* __restrict__ A, const u16* __restrict__ BT,
                 const float* __restrict__ bias, const float* __restrict__ res,
                 void* __restrict__ outv, int M, int N, int K)
{
    __shared__ u16 ldsA[128 * 32];
    __shared__ u16 ldsB[128 * 32];
    int tid = threadIdx.x;
    int wid = tid >> 6, lane = tid & 63;
    int wm = wid >> 1, wn = wid & 1;
    int quad = lane >> 4, l16 = lane & 15;
    int m0 = blockIdx.y << 7, n0 = blockIdx.x << 7;

    f32x4 acc[4][4] = {};

    const u16* gA0 = A  + (size_t)(m0 + wid * 32 + (lane >> 2)) * K + ((lane & 3) << 3);
    const u16* gA1 = gA0 + (size_t)16 * K;
    const u16* gB0 = BT + (size_t)(n0 + wid * 32 + (lane >> 2)) * K + ((lane & 3) << 3);
    const u16* gB1 = gB0 + (size_t)16 * K;
    u16* lA0 = ldsA + wid * 1024;           // wave-uniform LDS chunk bases
    u16* lA1 = ldsA + wid * 1024 + 512;
    u16* lB0 = ldsB + wid * 1024;
    u16* lB1 = ldsB + wid * 1024 + 512;

    for (int k0 = 0; k0 < K; k0 += 32) {
        gld16(lA0, gA0 + k0);
        gld16(lA1, gA1 + k0);
        gld16(lB0, gB0 + k0);
        gld16(lB1, gB1 + k0);
        __syncthreads();
        bf16x8 af[4], bf[4];
        #pragma unroll
        for (int t = 0; t < 4; t++) {
            af[t] = *(const bf16x8*)&ldsA[(wm * 64 + t * 16 + l16) * 32 + quad * 8];
            bf[t] = *(const bf16x8*)&ldsB[(wn * 64 + t * 16 + l16) * 32 + quad * 8];
        }
        #pragma unroll
        for (int i = 0; i < 4; i++)
            #pragma unroll
            for (int j = 0; j < 4; j++)
                acc[i][j] = __builtin_amdgcn_mfma_f32_16x16x32_bf16(af[i], bf[j], acc[i][j], 0, 0, 0);
        __syncthreads();
    }

    u16*   outb = (u16*)outv;
    float* outf = (float*)outv;
    int colb = n0 + wn * 64, rowb = m0 + wm * 64;
    #pragma unroll
    for (int j = 0; j < 4; j++) {
        int col = colb + j * 16 + l16;
        float bv = bias[col];
        #pragma unroll
        for (int i = 0; i < 4; i++) {
            int row0 = rowb + i * 16 + (quad << 2);
            #pragma unroll
            for (int r = 0; r < 4; r++) {
                float v = acc[i][j][r] + bv;
                size_t idx = (size_t)(row0 + r) * N + col;
                if (EPI == 2) {
                    outf[idx] = v + res[idx];
                } else {
                    if (EPI == 1) v = 0.5f * v * (1.0f + erff(v * 0.70710678118654752f));
                    outb[idx] = f2bf(v);
                }
            }
        }
    }
}

// ---------------------------------------------------------- flash attention
// qkv: [B,S,3D] bf16 (cols 0..D-1 = Q by [H,HD], D..2D-1 = K, 2D..3D-1 = V)
// av:  [B,S,D] bf16
__global__ __launch_bounds__(256)
void attn_kernel(const u16* __restrict__ qkv, u16* __restrict__ av)
{
    __shared__ u16 ldsK[4][64][32];    // [kk][key][d-part]
    __shared__ u16 ldsVT[2][128][32];  // [kstep][d][key-part]
    __shared__ u16 ldsP[4][16][72];    // per-wave P, padded stride
    int tid = threadIdx.x, wid = tid >> 6, lane = tid & 63;
    int quad = lane >> 4, l16 = lane & 15;
    int bh = blockIdx.y, b = bh >> 4, h = bh & 15;
    int q0 = blockIdx.x << 6;
    const u16* base = qkv + (size_t)b * S_ * (3 * D_);

    int qrow = q0 + wid * 16 + l16;
    const u16* qp = base + (size_t)qrow * (3 * D_) + h * HD_;
    bf16x8 aq[4];
    #pragma unroll
    for (int kk = 0; kk < 4; kk++)
        aq[kk] = *(const bf16x8*)(qp + kk * 32 + quad * 8);

    float m_i[4], l_i[4];
    f32x4 oacc[8] = {};
    #pragma unroll
    for (int r = 0; r < 4; r++) { m_i[r] = -1e30f; l_i[r] = 0.f; }

    const float scale = 0.088388347648318447f;  // 1/sqrt(128)
    int ntile = blockIdx.x + 1;
    for (int jt = 0; jt < ntile; jt++) {
        int j0 = jt << 6;
        // --- stage K tile (global_load_lds, [kk][key][32] layout) ---
        #pragma unroll
        for (int j = 0; j < 4; j++) {
            int c = wid * 4 + j;
            int kk = c >> 2, kb = c & 3;
            int key = (kb << 4) + (lane >> 2);
            const u16* g = base + (size_t)(j0 + key) * (3 * D_) + D_ + h * HD_
                         + kk * 32 + ((lane & 3) << 3);
            gld16((u16*)ldsK + c * 512, g);
        }
        // --- stage V tile transposed ---
        #pragma unroll
        for (int j = 0; j < 8; j++) {
            int e = (tid + (j << 8)) << 2;
            int row = e >> 7, col = e & 127;
            ushort4 vv = *(const ushort4*)(base + (size_t)(j0 + row) * (3 * D_)
                                           + 2 * D_ + h * HD_ + col);
            int ks = row >> 5, r5 = row & 31;
            ldsVT[ks][col + 0][r5] = vv.x;
            ldsVT[ks][col + 1][r5] = vv.y;
            ldsVT[ks][col + 2][r5] = vv.z;
            ldsVT[ks][col + 3][r5] = vv.w;
        }
        __syncthreads();
        // --- S = Q K^T ---
        f32x4 sacc[4] = {};
        #pragma unroll
        for (int kk = 0; kk < 4; kk++)
            #pragma unroll
            for (int n = 0; n < 4; n++) {
                bf16x8 bfr = *(const bf16x8*)&ldsK[kk][(n << 4) + l16][quad << 3];
                sacc[n] = __builtin_amdgcn_mfma_f32_16x16x32_bf16(aq[kk], bfr, sacc[n], 0, 0, 0);
            }
        // --- mask + online softmax ---
        float sv[4][4];
        float rowmax[4] = {-1e30f, -1e30f, -1e30f, -1e30f};
        bool diag = (jt == blockIdx.x);
        #pragma unroll
        for (int n = 0; n < 4; n++) {
            int key = j0 + (n << 4) + l16;
            #pragma unroll
            for (int r = 0; r < 4; r++) {
                float xv = sacc[n][r] * scale;
                if (diag) {
                    int qr = q0 + wid * 16 + (quad << 2) + r;
                    if (key > qr) xv = -1e30f;
                }
                sv[n][r] = xv;
                rowmax[r] = fmaxf(rowmax[r], xv);
            }
        }
        #pragma unroll
        for (int off = 1; off < 16; off <<= 1)
            #pragma unroll
            for (int r = 0; r < 4; r++)
                rowmax[r] = fmaxf(rowmax[r], __shfl_xor(rowmax[r], off, 64));
        float alpha[4], rsum[4];
        #pragma unroll
        for (int r = 0; r < 4; r++) {
            float mn = fmaxf(m_i[r], rowmax[r]);
            alpha[r] = __expf(m_i[r] - mn);
            m_i[r] = mn;
            rsum[r] = 0.f;
        }
        #pragma unroll
        for (int n = 0; n < 4; n++)
            #pragma unroll
            for (int r = 0; r < 4; r++) {
                float p = __expf(sv[n][r] - m_i[r]);
                rsum[r] += p;
                ldsP[wid][(quad << 2) + r][(n << 4) + l16] = f2bf(p);
            }
        #pragma unroll
        for (int off = 1; off < 16; off <<= 1)
            #pragma unroll
            for (int r = 0; r < 4; r++)
                rsum[r] += __shfl_xor(rsum[r], off, 64);
        #pragma unroll
        for (int r = 0; r < 4; r++)
            l_i[r] = l_i[r] * alpha[r] + rsum[r];
        #pragma unroll
        for (int n = 0; n < 8; n++)
            #pragma unroll
            for (int r = 0; r < 4; r++)
                oacc[n][r] *= alpha[r];
        __syncthreads();   // P visible to own-wave reads; cheap safety barrier
        // --- O += P V ---
        #pragma unroll
        for (int ks = 0; ks < 2; ks++) {
            bf16x8 pa = *(const bf16x8*)&ldsP[wid][l16][(ks << 5) + (quad << 3)];
            #pragma unroll
            for (int n = 0; n < 8; n++) {
                bf16x8 vb = *(const bf16x8*)&ldsVT[ks][(n << 4) + l16][quad << 3];
                oacc[n] = __builtin_amdgcn_mfma_f32_16x16x32_bf16(pa, vb, oacc[n], 0, 0, 0);
            }
        }
        __syncthreads();   // protect ldsK/ldsVT/ldsP for next tile
    }
    // --- write O / l ---
    #pragma unroll
    for (int r = 0; r < 4; r++) {
        float inv = 1.0f / l_i[r];
        int qr = q0 + wid * 16 + (quad << 2) + r;
        u16* op = av + (size_t)(b * S_ + qr) * D_ + h * HD_;
        #pragma unroll
        for (int n = 0; n < 8; n++)
            op[(n << 4) + l16] = f2bf(oacc[n][r] * inv);
    }
}

// ------------------------------------------------------------------- launch
extern "C" void kernel_launch(void* const* d_in, const int* in_sizes, int n_in,
                              void* d_out, int out_size, void* d_ws, size_t ws_size,
                              hipStream_t stream)
{
    const float* x     = (const float*)d_in[0];
    const float* ln1_g = (const float*)d_in[1];
    const float* ln1_b = (const float*)d_in[2];
    const float* qkv_w = (const float*)d_in[3];
    const float* qkv_b = (const float*)d_in[4];
    const float* out_w = (const float*)d_in[5];
    const float* out_b = (const float*)d_in[6];
    const float* ln2_g = (const float*)d_in[7];
    const float* ln2_b = (const float*)d_in[8];
    const float* w1    = (const float*)d_in[9];
    const float* b1    = (const float*)d_in[10];
    const float* w2    = (const float*)d_in[11];
    const float* b2    = (const float*)d_in[12];
    float* out = (float*)d_out;

    char* ws  = (char*)d_ws;
    u16* wT   = (u16*)ws;                        // 32 MiB: transposed bf16 weights
    u16* hbuf = (u16*)(ws + (32u << 20));        // 16 MiB: ln1-out / av / ln2-out
    u16* big  = (u16*)(ws + (48u << 20));        // 64 MiB: qkv, then ffn act
    u16* qkvb = big;
    u16* ffb  = big;

    dim3 blk(256);

    // 1. LN1: x -> hbuf (bf16)
    ln_kernel<<<dim3(B_ * S_), blk, 0, stream>>>(x, ln1_g, ln1_b, hbuf);
    // 2. qkv_w [2048][6144] -> wT [6144][2048]
    tcvt_kernel<<<dim3(6144 / 32, 2048 / 32), blk, 0, stream>>>(qkv_w, wT, 2048, 6144);
    // 3. qkv = hbuf @ qkv_w + qkv_b  (bf16 out)
    gemm_kernel<0><<<dim3(6144 / 128, 4096 / 128), blk, 0, stream>>>(
        hbuf, wT, qkv_b, nullptr, (void*)qkvb, 4096, 6144, 2048);
    // 4. attention -> hbuf (av, bf16)
    attn_kernel<<<dim3(S_ / 64, B_ * H_), blk, 0, stream>>>(qkvb, hbuf);
    // 5. out_w [2048][2048] -> wT
    tcvt_kernel<<<dim3(2048 / 32, 2048 / 32), blk, 0, stream>>>(out_w, wT, 2048, 2048);
    // 6. x1 = x + av @ out_w + out_b  (fp32, into d_out)
    gemm_kernel<2><<<dim3(2048 / 128, 4096 / 128), blk, 0, stream>>>(
        hbuf, wT, out_b, x, (void*)out, 4096, 2048, 2048);
    // 7. LN2: x1 -> hbuf (bf16)
    ln_kernel<<<dim3(B_ * S_), blk, 0, stream>>>(out, ln2_g, ln2_b, hbuf);
    // 8. w1 [2048][8192] -> wT [8192][2048]
    tcvt_kernel<<<dim3(8192 / 32, 2048 / 32), blk, 0, stream>>>(w1, wT, 2048, 8192);
    // 9. ff = gelu(hbuf @ w1 + b1)  (bf16)
    gemm_kernel<1><<<dim3(8192 / 128, 4096 / 128), blk, 0, stream>>>(
        hbuf, wT, b1, nullptr, (void*)ffb, 4096, 8192, 2048);
    // 10. w2 [8192][2048] -> wT [2048][8192]
    tcvt_kernel<<<dim3(2048 / 32, 8192 / 32), blk, 0, stream>>>(w2, wT, 8192, 2048);
    // 11. out = x1 + ff @ w2 + b2  (fp32, reads+writes d_out)
    gemm_kernel<2><<<dim3(2048 / 128, 4096 / 128), blk, 0, stream>>>(
        ffb, wT, b2, out, (void*)out, 4096, 2048, 8192);
}

// Round 2
// 1024.706 us; speedup vs baseline: 1.4362x; 1.4362x over previous
//
#include <hip/hip_runtime.h>
#include <hip/hip_bf16.h>

#define B_  2
#define S_  2048
#define D_  2048
#define H_  16
#define HD_ 128
#define FF_ 8192

typedef __bf16 bf16x8 __attribute__((ext_vector_type(8)));
typedef float  f32x4  __attribute__((ext_vector_type(4)));
typedef unsigned short u16;
typedef u16 u16x8 __attribute__((ext_vector_type(8)));

__device__ __forceinline__ u16 f2bf(float f) {
    union { float f; unsigned u; } c; c.f = f;
    unsigned u = c.u;
    u += 0x7fffu + ((u >> 16) & 1u);   // RNE
    return (u16)(u >> 16);
}

__device__ __forceinline__ void gld16(void* lds, const void* g) {
    __builtin_amdgcn_global_load_lds(
        (const __attribute__((address_space(1))) unsigned int*)g,
        (__attribute__((address_space(3))) unsigned int*)lds,
        16, 0, 0);
}

// ---------------------------------------------------------------- LayerNorm
__global__ __launch_bounds__(256)
void ln_kernel(const float* __restrict__ x, const float* __restrict__ g,
               const float* __restrict__ bb, u16* __restrict__ out)
{
    int row = blockIdx.x, tid = threadIdx.x;
    const float4* xr = (const float4*)(x + (size_t)row * D_);
    float4 a = xr[tid], c = xr[tid + 256];
    float s  = a.x + a.y + a.z + a.w + c.x + c.y + c.z + c.w;
    float s2 = a.x*a.x + a.y*a.y + a.z*a.z + a.w*a.w
             + c.x*c.x + c.y*c.y + c.z*c.z + c.w*c.w;
    #pragma unroll
    for (int off = 32; off > 0; off >>= 1) {
        s  += __shfl_down(s,  off, 64);
        s2 += __shfl_down(s2, off, 64);
    }
    __shared__ float red[16];
    __shared__ float mr[2];
    int wid = tid >> 6, lane = tid & 63;
    if (lane == 0) { red[wid] = s; red[8 + wid] = s2; }
    __syncthreads();
    if (tid == 0) {
        float ts = red[0] + red[1] + red[2] + red[3];
        float t2 = red[8] + red[9] + red[10] + red[11];
        float mu = ts * (1.0f / D_);
        float var = t2 * (1.0f / D_) - mu * mu;
        mr[0] = mu; mr[1] = rsqrtf(var + 1e-5f);
    }
    __syncthreads();
    float mu = mr[0], rstd = mr[1];
    const float4* gg = (const float4*)g;
    const float4* bv = (const float4*)bb;
    float4 g0 = gg[tid], g1 = gg[tid + 256];
    float4 b0 = bv[tid], b1 = bv[tid + 256];
    u16* orow = out + (size_t)row * D_;
    ushort4 o0, o1;
    o0.x = f2bf((a.x - mu) * rstd * g0.x + b0.x);
    o0.y = f2bf((a.y - mu) * rstd * g0.y + b0.y);
    o0.z = f2bf((a.z - mu) * rstd * g0.z + b0.z);
    o0.w = f2bf((a.w - mu) * rstd * g0.w + b0.w);
    o1.x = f2bf((c.x - mu) * rstd * g1.x + b1.x);
    o1.y = f2bf((c.y - mu) * rstd * g1.y + b1.y);
    o1.z = f2bf((c.z - mu) * rstd * g1.z + b1.z);
    o1.w = f2bf((c.w - mu) * rstd * g1.w + b1.w);
    *(ushort4*)&orow[tid * 4]         = o0;
    *(ushort4*)&orow[(tid + 256) * 4] = o1;
}

// ----------------------------------------------- transpose + fp32->bf16 cast
__global__ __launch_bounds__(256)
void tcvt_kernel(const float* __restrict__ W, u16* __restrict__ WT, int K, int N)
{
    __shared__ float t[32][33];
    int n0 = blockIdx.x << 5, k0 = blockIdx.y << 5;
    int tx = threadIdx.x & 31, ty = threadIdx.x >> 5;
    #pragma unroll
    for (int i = 0; i < 32; i += 8)
        t[ty + i][tx] = W[(size_t)(k0 + ty + i) * N + n0 + tx];
    __syncthreads();
    #pragma unroll
    for (int i = 0; i < 32; i += 8)
        WT[(size_t)(n0 + ty + i) * K + k0 + tx] = f2bf(t[tx][ty + i]);
}

// ---------------------------------------------------------------- GEMM bf16
template<int EPI>
__global__ __launch_bounds__(256)
void gemm_kernel(const u16* __restrict__ A, const u16* __restrict__ BT,
                 const float* __restrict__ bias, const float* __restrict__ res,
                 void* __restrict__ outv, int M, int N, int K)
{
    __shared__ u16 ldsA[128 * 32];
    __shared__ u16 ldsB[128 * 32];
    int tid = threadIdx.x;
    int wid = tid >> 6, lane = tid & 63;
    int wm = wid >> 1, wn = wid & 1;
    int quad = lane >> 4, l16 = lane & 15;
    int m0 = blockIdx.y << 7, n0 = blockIdx.x << 7;

    f32x4 acc[4][4] = {};

    const u16* gA0 = A  + (size_t)(m0 + wid * 32 + (lane >> 2)) * K + ((lane & 3) << 3);
    const u16* gA1 = gA0 + (size_t)16 * K;
    const u16* gB0 = BT + (size_t)(n0 + wid * 32 + (lane >> 2)) * K + ((lane & 3) << 3);
    const u16* gB1 = gB0 + (size_t)16 * K;
    u16* lA0 = ldsA + wid * 1024;
    u16* lA1 = ldsA + wid * 1024 + 512;
    u16* lB0 = ldsB + wid * 1024;
    u16* lB1 = ldsB + wid * 1024 + 512;

    for (int k0 = 0; k0 < K; k0 += 32) {
        gld16(lA0, gA0 + k0);
        gld16(lA1, gA1 + k0);
        gld16(lB0, gB0 + k0);
        gld16(lB1, gB1 + k0);
        __syncthreads();
        bf16x8 af[4], bf[4];
        #pragma unroll
        for (int t = 0; t < 4; t++) {
            af[t] = *(const bf16x8*)&ldsA[(wm * 64 + t * 16 + l16) * 32 + quad * 8];
            bf[t] = *(const bf16x8*)&ldsB[(wn * 64 + t * 16 + l16) * 32 + quad * 8];
        }
        #pragma unroll
        for (int i = 0; i < 4; i++)
            #pragma unroll
            for (int j = 0; j < 4; j++)
                acc[i][j] = __builtin_amdgcn_mfma_f32_16x16x32_bf16(af[i], bf[j], acc[i][j], 0, 0, 0);
        __syncthreads();
    }

    u16*   outb = (u16*)outv;
    float* outf = (float*)outv;
    int colb = n0 + wn * 64, rowb = m0 + wm * 64;
    #pragma unroll
    for (int j = 0; j < 4; j++) {
        int col = colb + j * 16 + l16;
        float bv = bias[col];
        #pragma unroll
        for (int i = 0; i < 4; i++) {
            int row0 = rowb + i * 16 + (quad << 2);
            #pragma unroll
            for (int r = 0; r < 4; r++) {
                float v = acc[i][j][r] + bv;
                size_t idx = (size_t)(row0 + r) * N + col;
                if (EPI == 2) {
                    outf[idx] = v + res[idx];
                } else {
                    if (EPI == 1) v = 0.5f * v * (1.0f + erff(v * 0.70710678118654752f));
                    outb[idx] = f2bf(v);
                }
            }
        }
    }
}

// ---------------------------------------------------------- flash attention
// Block: 128 q-rows x 64-key tiles. 4 waves; wave handles two 16-row sets
// (rows q0 + set*64 + wid*16 .. +15). V^T stored as packed key-pair dwords:
// ldsVT[d][kp] = V[2kp] | V[2kp+1]<<16  (stride 36 dw: d-delta = 4 banks,
// write lanes span consecutive dwords -> conflict-free).
__global__ __launch_bounds__(256, 2)
void attn_kernel(const u16* __restrict__ qkv, u16* __restrict__ av)
{
    __shared__ u16 ldsK[4][64][32];          // 16 KB  [d-chunk][key][32]
    __shared__ unsigned ldsVT[128][36];      // 18 KB  [d][key-pair]
    __shared__ u16 ldsP[4][32][72];          // 18 KB  per-wave P (2 sets)
    int tid = threadIdx.x, wid = tid >> 6, lane = tid & 63;
    int quad = lane >> 4, l16 = lane & 15;
    int bh = blockIdx.y, b = bh >> 4, h = bh & 15;
    int qx = gridDim.x - 1 - blockIdx.x;     // heavy causal blocks first
    int q0 = qx << 7;
    const u16* base = qkv + (size_t)b * S_ * (3 * D_);

    bf16x8 aq[2][4];
    #pragma unroll
    for (int set = 0; set < 2; set++) {
        int qrow = q0 + set * 64 + wid * 16 + l16;
        const u16* qp = base + (size_t)qrow * (3 * D_) + h * HD_;
        #pragma unroll
        for (int kk = 0; kk < 4; kk++)
            aq[set][kk] = *(const bf16x8*)(qp + kk * 32 + quad * 8);
    }

    float m_i[2][4], l_i[2][4];
    f32x4 oacc[2][8] = {};
    #pragma unroll
    for (int s = 0; s < 2; s++)
        #pragma unroll
        for (int r = 0; r < 4; r++) { m_i[s][r] = -1e30f; l_i[s][r] = 0.f; }

    const float scale = 0.088388347648318447f;  // 1/sqrt(128)
    int ntile = 2 * qx + 2;
    for (int jt = 0; jt < ntile; jt++) {
        int j0 = jt << 6;
        // --- stage K tile: 4 gld16 per wave, [kk][key][32] ---
        #pragma unroll
        for (int j = 0; j < 4; j++) {
            int c = wid * 4 + j;
            int kk = c >> 2, kb = c & 3;
            int key = (kb << 4) + (lane >> 2);
            const u16* g = base + (size_t)(j0 + key) * (3 * D_) + D_ + h * HD_
                         + kk * 32 + ((lane & 3) << 3);
            gld16((u16*)ldsK + c * 512, g);
        }
        // --- stage V^T packed: wave covers d in [wid*32, wid*32+32) ---
        {
            int kp = lane & 31, dhalf = lane >> 5;
            #pragma unroll
            for (int p = 0; p < 2; p++) {
                int doff = wid * 32 + p * 16 + dhalf * 8;
                const u16* g0 = base + (size_t)(j0 + 2 * kp) * (3 * D_)
                              + 2 * D_ + h * HD_ + doff;
                u16x8 v0 = *(const u16x8*)g0;
                u16x8 v1 = *(const u16x8*)(g0 + 3 * D_);
                #pragma unroll
                for (int k = 0; k < 8; k++)
                    ldsVT[doff + k][kp] = (unsigned)v0[k] | ((unsigned)v1[k] << 16);
            }
        }
        __syncthreads();
        // --- S = Q K^T (both row-sets share each K fragment) ---
        f32x4 sacc[2][4] = {};
        #pragma unroll
        for (int kk = 0; kk < 4; kk++)
            #pragma unroll
            for (int n = 0; n < 4; n++) {
                bf16x8 bfr = *(const bf16x8*)&ldsK[kk][(n << 4) + l16][quad << 3];
                sacc[0][n] = __builtin_amdgcn_mfma_f32_16x16x32_bf16(aq[0][kk], bfr, sacc[0][n], 0, 0, 0);
                sacc[1][n] = __builtin_amdgcn_mfma_f32_16x16x32_bf16(aq[1][kk], bfr, sacc[1][n], 0, 0, 0);
            }
        // --- mask + online softmax (per row-set) ---
        #pragma unroll
        for (int set = 0; set < 2; set++) {
            float rowmax[4] = {-1e30f, -1e30f, -1e30f, -1e30f};
            #pragma unroll
            for (int n = 0; n < 4; n++) {
                int key = j0 + (n << 4) + l16;
                #pragma unroll
                for (int r = 0; r < 4; r++) {
                    float xv = sacc[set][n][r] * scale;
                    int qr = q0 + set * 64 + wid * 16 + (quad << 2) + r;
                    if (key > qr) xv = -1e30f;
                    sacc[set][n][r] = xv;
                    rowmax[r] = fmaxf(rowmax[r], xv);
                }
            }
            #pragma unroll
            for (int off = 1; off < 16; off <<= 1)
                #pragma unroll
                for (int r = 0; r < 4; r++)
                    rowmax[r] = fmaxf(rowmax[r], __shfl_xor(rowmax[r], off, 64));
            float alpha[4], rsum[4];
            #pragma unroll
            for (int r = 0; r < 4; r++) {
                float mn = fmaxf(m_i[set][r], rowmax[r]);
                alpha[r] = __expf(m_i[set][r] - mn);
                m_i[set][r] = mn;
                rsum[r] = 0.f;
            }
            #pragma unroll
            for (int n = 0; n < 4; n++)
                #pragma unroll
                for (int r = 0; r < 4; r++) {
                    float p = __expf(sacc[set][n][r] - m_i[set][r]);
                    rsum[r] += p;
                    ldsP[wid][set * 16 + (quad << 2) + r][(n << 4) + l16] = f2bf(p);
                }
            #pragma unroll
            for (int off = 1; off < 16; off <<= 1)
                #pragma unroll
                for (int r = 0; r < 4; r++)
                    rsum[r] += __shfl_xor(rsum[r], off, 64);
            #pragma unroll
            for (int r = 0; r < 4; r++)
                l_i[set][r] = l_i[set][r] * alpha[r] + rsum[r];
            #pragma unroll
            for (int n = 0; n < 8; n++)
                #pragma unroll
                for (int r = 0; r < 4; r++)
                    oacc[set][n][r] *= alpha[r];
        }
        // --- O += P V (P is wave-private: no barrier needed before reads) ---
        #pragma unroll
        for (int ks = 0; ks < 2; ks++) {
            bf16x8 pa0 = *(const bf16x8*)&ldsP[wid][l16]     [(ks << 5) + (quad << 3)];
            bf16x8 pa1 = *(const bf16x8*)&ldsP[wid][16 + l16][(ks << 5) + (quad << 3)];
            #pragma unroll
            for (int n = 0; n < 8; n++) {
                bf16x8 vb = *(const bf16x8*)&ldsVT[(n << 4) + l16][(ks << 4) + (quad << 2)];
                oacc[0][n] = __builtin_amdgcn_mfma_f32_16x16x32_bf16(pa0, vb, oacc[0][n], 0, 0, 0);
                oacc[1][n] = __builtin_amdgcn_mfma_f32_16x16x32_bf16(pa1, vb, oacc[1][n], 0, 0, 0);
            }
        }
        __syncthreads();   // protect ldsK/ldsVT for next tile's staging
    }
    // --- write O ---
    #pragma unroll
    for (int set = 0; set < 2; set++)
        #pragma unroll
        for (int r = 0; r < 4; r++) {
            float inv = 1.0f / l_i[set][r];
            int qr = q0 + set * 64 + wid * 16 + (quad << 2) + r;
            u16* op = av + (size_t)(b * S_ + qr) * D_ + h * HD_;
            #pragma unroll
            for (int n = 0; n < 8; n++)
                op[(n << 4) + l16] = f2bf(oacc[set][n][r] * inv);
        }
}

// ------------------------------------------------------------------- launch
extern "C" void kernel_launch(void* const* d_in, const int* in_sizes, int n_in,
                              void* d_out, int out_size, void* d_ws, size_t ws_size,
                              hipStream_t stream)
{
    const float* x     = (const float*)d_in[0];
    const float* ln1_g = (const float*)d_in[1];
    const float* ln1_b = (const float*)d_in[2];
    const float* qkv_w = (const float*)d_in[3];
    const float* qkv_b = (const float*)d_in[4];
    const float* out_w = (const float*)d_in[5];
    const float* out_b = (const float*)d_in[6];
    const float* ln2_g = (const float*)d_in[7];
    const float* ln2_b = (const float*)d_in[8];
    const float* w1    = (const float*)d_in[9];
    const float* b1    = (const float*)d_in[10];
    const float* w2    = (const float*)d_in[11];
    const float* b2    = (const float*)d_in[12];
    float* out = (float*)d_out;

    char* ws  = (char*)d_ws;
    u16* wT   = (u16*)ws;                        // 32 MiB: transposed bf16 weights
    u16* hbuf = (u16*)(ws + (32u << 20));        // 16 MiB: ln1-out / av / ln2-out
    u16* big  = (u16*)(ws + (48u << 20));        // 64 MiB: qkv, then ffn act
    u16* qkvb = big;
    u16* ffb  = big;

    dim3 blk(256);

    ln_kernel<<<dim3(B_ * S_), blk, 0, stream>>>(x, ln1_g, ln1_b, hbuf);
    tcvt_kernel<<<dim3(6144 / 32, 2048 / 32), blk, 0, stream>>>(qkv_w, wT, 2048, 6144);
    gemm_kernel<0><<<dim3(6144 / 128, 4096 / 128), blk, 0, stream>>>(
        hbuf, wT, qkv_b, nullptr, (void*)qkvb, 4096, 6144, 2048);
    attn_kernel<<<dim3(S_ / 128, B_ * H_), blk, 0, stream>>>(qkvb, hbuf);
    tcvt_kernel<<<dim3(2048 / 32, 2048 / 32), blk, 0, stream>>>(out_w, wT, 2048, 2048);
    gemm_kernel<2><<<dim3(2048 / 128, 4096 / 128), blk, 0, stream>>>(
        hbuf, wT, out_b, x, (void*)out, 4096, 2048, 2048);
    ln_kernel<<<dim3(B_ * S_), blk, 0, stream>>>(out, ln2_g, ln2_b, hbuf);
    tcvt_kernel<<<dim3(8192 / 32, 2048 / 32), blk, 0, stream>>>(w1, wT, 2048, 8192);
    gemm_kernel<1><<<dim3(8192 / 128, 4096 / 128), blk, 0, stream>>>(
        hbuf, wT, b1, nullptr, (void*)ffb, 4096, 8192, 2048);
    tcvt_kernel<<<dim3(2048 / 32, 8192 / 32), blk, 0, stream>>>(w2, wT, 8192, 2048);
    gemm_kernel<2><<<dim3(2048 / 128, 4096 / 128), blk, 0, stream>>>(
        ffb, wT, b2, out, (void*)out, 4096, 2048, 8192);
}

// Round 3
// 951.680 us; speedup vs baseline: 1.5464x; 1.0767x over previous
//
#include <hip/hip_runtime.h>
#include <hip/hip_bf16.h>

#define B_  2
#define S_  2048
#define D_  2048
#define H_  16
#define HD_ 128
#define FF_ 8192

typedef __bf16 bf16x8 __attribute__((ext_vector_type(8)));
typedef float  f32x4  __attribute__((ext_vector_type(4)));
typedef unsigned short u16;
typedef u16 u16x8 __attribute__((ext_vector_type(8)));

__device__ __forceinline__ u16 f2bf(float f) {
    union { float f; unsigned u; } c; c.f = f;
    unsigned u = c.u;
    u += 0x7fffu + ((u >> 16) & 1u);   // RNE
    return (u16)(u >> 16);
}

__device__ __forceinline__ void gld16(void* lds, const void* g) {
    __builtin_amdgcn_global_load_lds(
        (const __attribute__((address_space(1))) unsigned int*)g,
        (__attribute__((address_space(3))) unsigned int*)lds,
        16, 0, 0);
}

// ---------------------------------------------------------------- LayerNorm
__global__ __launch_bounds__(256)
void ln_kernel(const float* __restrict__ x, const float* __restrict__ g,
               const float* __restrict__ bb, u16* __restrict__ out)
{
    int row = blockIdx.x, tid = threadIdx.x;
    const float4* xr = (const float4*)(x + (size_t)row * D_);
    float4 a = xr[tid], c = xr[tid + 256];
    float s  = a.x + a.y + a.z + a.w + c.x + c.y + c.z + c.w;
    float s2 = a.x*a.x + a.y*a.y + a.z*a.z + a.w*a.w
             + c.x*c.x + c.y*c.y + c.z*c.z + c.w*c.w;
    #pragma unroll
    for (int off = 32; off > 0; off >>= 1) {
        s  += __shfl_down(s,  off, 64);
        s2 += __shfl_down(s2, off, 64);
    }
    __shared__ float red[16];
    __shared__ float mr[2];
    int wid = tid >> 6, lane = tid & 63;
    if (lane == 0) { red[wid] = s; red[8 + wid] = s2; }
    __syncthreads();
    if (tid == 0) {
        float ts = red[0] + red[1] + red[2] + red[3];
        float t2 = red[8] + red[9] + red[10] + red[11];
        float mu = ts * (1.0f / D_);
        float var = t2 * (1.0f / D_) - mu * mu;
        mr[0] = mu; mr[1] = rsqrtf(var + 1e-5f);
    }
    __syncthreads();
    float mu = mr[0], rstd = mr[1];
    const float4* gg = (const float4*)g;
    const float4* bv = (const float4*)bb;
    float4 g0 = gg[tid], g1 = gg[tid + 256];
    float4 b0 = bv[tid], b1 = bv[tid + 256];
    u16* orow = out + (size_t)row * D_;
    ushort4 o0, o1;
    o0.x = f2bf((a.x - mu) * rstd * g0.x + b0.x);
    o0.y = f2bf((a.y - mu) * rstd * g0.y + b0.y);
    o0.z = f2bf((a.z - mu) * rstd * g0.z + b0.z);
    o0.w = f2bf((a.w - mu) * rstd * g0.w + b0.w);
    o1.x = f2bf((c.x - mu) * rstd * g1.x + b1.x);
    o1.y = f2bf((c.y - mu) * rstd * g1.y + b1.y);
    o1.z = f2bf((c.z - mu) * rstd * g1.z + b1.z);
    o1.w = f2bf((c.w - mu) * rstd * g1.w + b1.w);
    *(ushort4*)&orow[tid * 4]         = o0;
    *(ushort4*)&orow[(tid + 256) * 4] = o1;
}

// ----------------------------------------------- transpose + fp32->bf16 cast
__global__ __launch_bounds__(256)
void tcvt_kernel(const float* __restrict__ W, u16* __restrict__ WT, int K, int N)
{
    __shared__ float t[32][33];
    int n0 = blockIdx.x << 5, k0 = blockIdx.y << 5;
    int tx = threadIdx.x & 31, ty = threadIdx.x >> 5;
    #pragma unroll
    for (int i = 0; i < 32; i += 8)
        t[ty + i][tx] = W[(size_t)(k0 + ty + i) * N + n0 + tx];
    __syncthreads();
    #pragma unroll
    for (int i = 0; i < 32; i += 8)
        WT[(size_t)(n0 + ty + i) * K + k0 + tx] = f2bf(t[tx][ty + i]);
}

// ---------------------------------------------------------------- GEMM bf16
// C[M,N] = A[M,K](bf16,row) * BT[N,K](bf16,row)^T + bias
// 128x128 tile, BK=64, XOR-swizzled LDS chunks (conflict-free b128 reads,
// contiguous gld16 dests). 32 MFMA per barrier pair. 1D grid, 16-wide N bands.
template<int EPI>
__global__ __launch_bounds__(256)
void gemm_kernel(const u16* __restrict__ A, const u16* __restrict__ BT,
                 const float* __restrict__ bias, const float* __restrict__ res,
                 void* __restrict__ outv, int M, int N, int K)
{
    __shared__ u16 ldsA[128 * 64];
    __shared__ u16 ldsB[128 * 64];
    int tid = threadIdx.x;
    int wid = tid >> 6, lane = tid & 63;
    int wm = wid >> 1, wn = wid & 1;
    int quad = lane >> 4, l16 = lane & 15;

    // block swizzle: bands of 16 N-tiles, sweep all M within a band
    int tiles_m = M >> 7;
    int bandsz = tiles_m << 4;
    int lin = blockIdx.x;
    int band = lin / bandsz, rr = lin % bandsz;
    int m0 = (rr >> 4) << 7;
    int n0 = ((band << 4) + (rr & 15)) << 7;

    f32x4 acc[4][4] = {};

    int r8 = lane >> 3, c8 = lane & 7;
    int gc = (c8 ^ (r8 & 7)) << 3;           // XOR-swizzled source chunk
    const u16* pA = A  + (size_t)(m0 + wid * 32 + r8) * K + gc;
    const u16* pB = BT + (size_t)(n0 + wid * 32 + r8) * K + gc;
    u16* lA = ldsA + wid * 32 * 64;
    u16* lB = ldsB + wid * 32 * 64;
    int sw = l16 & 7;

    for (int k0 = 0; k0 < K; k0 += 64) {
        #pragma unroll
        for (int j = 0; j < 4; j++) {
            gld16(lA + j * 512, pA + (size_t)j * 8 * K + k0);
            gld16(lB + j * 512, pB + (size_t)j * 8 * K + k0);
        }
        __syncthreads();
        #pragma unroll
        for (int kk = 0; kk < 2; kk++) {
            bf16x8 af[4], bf[4];
            int co0 = ((kk * 4 + 0) ^ sw) << 3;
            int co1 = ((kk * 4 + 1) ^ sw) << 3;
            int co2 = ((kk * 4 + 2) ^ sw) << 3;
            int co3 = ((kk * 4 + 3) ^ sw) << 3;
            int co = quad == 0 ? co0 : quad == 1 ? co1 : quad == 2 ? co2 : co3;
            #pragma unroll
            for (int t = 0; t < 4; t++) {
                af[t] = *(const bf16x8*)&ldsA[(wm * 64 + t * 16 + l16) * 64 + co];
                bf[t] = *(const bf16x8*)&ldsB[(wn * 64 + t * 16 + l16) * 64 + co];
            }
            #pragma unroll
            for (int i = 0; i < 4; i++)
                #pragma unroll
                for (int j = 0; j < 4; j++)
                    acc[i][j] = __builtin_amdgcn_mfma_f32_16x16x32_bf16(af[i], bf[j], acc[i][j], 0, 0, 0);
        }
        __syncthreads();
    }

    u16*   outb = (u16*)outv;
    float* outf = (float*)outv;
    int colb = n0 + wn * 64, rowb = m0 + wm * 64;
    #pragma unroll
    for (int j = 0; j < 4; j++) {
        int col = colb + j * 16 + l16;
        float bv = bias[col];
        #pragma unroll
        for (int i = 0; i < 4; i++) {
            int row0 = rowb + i * 16 + (quad << 2);
            #pragma unroll
            for (int r = 0; r < 4; r++) {
                float v = acc[i][j][r] + bv;
                size_t idx = (size_t)(row0 + r) * N + col;
                if (EPI == 2) {
                    outf[idx] = v + res[idx];
                } else {
                    if (EPI == 1) v = 0.5f * v * (1.0f + erff(v * 0.70710678118654752f));
                    outb[idx] = f2bf(v);
                }
            }
        }
    }
}

// ---------------------------------------------------------- flash attention
__global__ __launch_bounds__(256, 2)
void attn_kernel(const u16* __restrict__ qkv, u16* __restrict__ av)
{
    __shared__ u16 ldsK[4][64][32];          // 16 KB  [d-chunk][key][32]
    __shared__ unsigned ldsVT[128][36];      // 18 KB  [d][key-pair]
    __shared__ u16 ldsP[4][32][72];          // 18 KB  per-wave P (2 sets)
    int tid = threadIdx.x, wid = tid >> 6, lane = tid & 63;
    int quad = lane >> 4, l16 = lane & 15;
    int bh = blockIdx.y, b = bh >> 4, h = bh & 15;
    int qx = gridDim.x - 1 - blockIdx.x;     // heavy causal blocks first
    int q0 = qx << 7;
    const u16* base = qkv + (size_t)b * S_ * (3 * D_);

    bf16x8 aq[2][4];
    #pragma unroll
    for (int set = 0; set < 2; set++) {
        int qrow = q0 + set * 64 + wid * 16 + l16;
        const u16* qp = base + (size_t)qrow * (3 * D_) + h * HD_;
        #pragma unroll
        for (int kk = 0; kk < 4; kk++)
            aq[set][kk] = *(const bf16x8*)(qp + kk * 32 + quad * 8);
    }

    float m_i[2][4], l_i[2][4];
    f32x4 oacc[2][8] = {};
    #pragma unroll
    for (int s = 0; s < 2; s++)
        #pragma unroll
        for (int r = 0; r < 4; r++) { m_i[s][r] = -1e30f; l_i[s][r] = 0.f; }

    const float scale = 0.088388347648318447f;  // 1/sqrt(128)
    int ntile = 2 * qx + 2;
    for (int jt = 0; jt < ntile; jt++) {
        int j0 = jt << 6;
        #pragma unroll
        for (int j = 0; j < 4; j++) {
            int c = wid * 4 + j;
            int kk = c >> 2, kb = c & 3;
            int key = (kb << 4) + (lane >> 2);
            const u16* g = base + (size_t)(j0 + key) * (3 * D_) + D_ + h * HD_
                         + kk * 32 + ((lane & 3) << 3);
            gld16((u16*)ldsK + c * 512, g);
        }
        {
            int kp = lane & 31, dhalf = lane >> 5;
            #pragma unroll
            for (int p = 0; p < 2; p++) {
                int doff = wid * 32 + p * 16 + dhalf * 8;
                const u16* g0 = base + (size_t)(j0 + 2 * kp) * (3 * D_)
                              + 2 * D_ + h * HD_ + doff;
                u16x8 v0 = *(const u16x8*)g0;
                u16x8 v1 = *(const u16x8*)(g0 + 3 * D_);
                #pragma unroll
                for (int k = 0; k < 8; k++)
                    ldsVT[doff + k][kp] = (unsigned)v0[k] | ((unsigned)v1[k] << 16);
            }
        }
        __syncthreads();
        f32x4 sacc[2][4] = {};
        #pragma unroll
        for (int kk = 0; kk < 4; kk++)
            #pragma unroll
            for (int n = 0; n < 4; n++) {
                bf16x8 bfr = *(const bf16x8*)&ldsK[kk][(n << 4) + l16][quad << 3];
                sacc[0][n] = __builtin_amdgcn_mfma_f32_16x16x32_bf16(aq[0][kk], bfr, sacc[0][n], 0, 0, 0);
                sacc[1][n] = __builtin_amdgcn_mfma_f32_16x16x32_bf16(aq[1][kk], bfr, sacc[1][n], 0, 0, 0);
            }
        #pragma unroll
        for (int set = 0; set < 2; set++) {
            float rowmax[4] = {-1e30f, -1e30f, -1e30f, -1e30f};
            #pragma unroll
            for (int n = 0; n < 4; n++) {
                int key = j0 + (n << 4) + l16;
                #pragma unroll
                for (int r = 0; r < 4; r++) {
                    float xv = sacc[set][n][r] * scale;
                    int qr = q0 + set * 64 + wid * 16 + (quad << 2) + r;
                    if (key > qr) xv = -1e30f;
                    sacc[set][n][r] = xv;
                    rowmax[r] = fmaxf(rowmax[r], xv);
                }
            }
            #pragma unroll
            for (int off = 1; off < 16; off <<= 1)
                #pragma unroll
                for (int r = 0; r < 4; r++)
                    rowmax[r] = fmaxf(rowmax[r], __shfl_xor(rowmax[r], off, 64));
            float alpha[4], rsum[4];
            #pragma unroll
            for (int r = 0; r < 4; r++) {
                float mn = fmaxf(m_i[set][r], rowmax[r]);
                alpha[r] = __expf(m_i[set][r] - mn);
                m_i[set][r] = mn;
                rsum[r] = 0.f;
            }
            #pragma unroll
            for (int n = 0; n < 4; n++)
                #pragma unroll
                for (int r = 0; r < 4; r++) {
                    float p = __expf(sacc[set][n][r] - m_i[set][r]);
                    rsum[r] += p;
                    ldsP[wid][set * 16 + (quad << 2) + r][(n << 4) + l16] = f2bf(p);
                }
            #pragma unroll
            for (int off = 1; off < 16; off <<= 1)
                #pragma unroll
                for (int r = 0; r < 4; r++)
                    rsum[r] += __shfl_xor(rsum[r], off, 64);
            #pragma unroll
            for (int r = 0; r < 4; r++)
                l_i[set][r] = l_i[set][r] * alpha[r] + rsum[r];
            #pragma unroll
            for (int n = 0; n < 8; n++)
                #pragma unroll
                for (int r = 0; r < 4; r++)
                    oacc[set][n][r] *= alpha[r];
        }
        #pragma unroll
        for (int ks = 0; ks < 2; ks++) {
            bf16x8 pa0 = *(const bf16x8*)&ldsP[wid][l16]     [(ks << 5) + (quad << 3)];
            bf16x8 pa1 = *(const bf16x8*)&ldsP[wid][16 + l16][(ks << 5) + (quad << 3)];
            #pragma unroll
            for (int n = 0; n < 8; n++) {
                bf16x8 vb = *(const bf16x8*)&ldsVT[(n << 4) + l16][(ks << 4) + (quad << 2)];
                oacc[0][n] = __builtin_amdgcn_mfma_f32_16x16x32_bf16(pa0, vb, oacc[0][n], 0, 0, 0);
                oacc[1][n] = __builtin_amdgcn_mfma_f32_16x16x32_bf16(pa1, vb, oacc[1][n], 0, 0, 0);
            }
        }
        __syncthreads();
    }
    #pragma unroll
    for (int set = 0; set < 2; set++)
        #pragma unroll
        for (int r = 0; r < 4; r++) {
            float inv = 1.0f / l_i[set][r];
            int qr = q0 + set * 64 + wid * 16 + (quad << 2) + r;
            u16* op = av + (size_t)(b * S_ + qr) * D_ + h * HD_;
            #pragma unroll
            for (int n = 0; n < 8; n++)
                op[(n << 4) + l16] = f2bf(oacc[set][n][r] * inv);
        }
}

// ------------------------------------------------------------------- launch
extern "C" void kernel_launch(void* const* d_in, const int* in_sizes, int n_in,
                              void* d_out, int out_size, void* d_ws, size_t ws_size,
                              hipStream_t stream)
{
    const float* x     = (const float*)d_in[0];
    const float* ln1_g = (const float*)d_in[1];
    const float* ln1_b = (const float*)d_in[2];
    const float* qkv_w = (const float*)d_in[3];
    const float* qkv_b = (const float*)d_in[4];
    const float* out_w = (const float*)d_in[5];
    const float* out_b = (const float*)d_in[6];
    const float* ln2_g = (const float*)d_in[7];
    const float* ln2_b = (const float*)d_in[8];
    const float* w1    = (const float*)d_in[9];
    const float* b1    = (const float*)d_in[10];
    const float* w2    = (const float*)d_in[11];
    const float* b2    = (const float*)d_in[12];
    float* out = (float*)d_out;

    char* ws  = (char*)d_ws;
    u16* wT   = (u16*)ws;                        // 32 MiB: transposed bf16 weights
    u16* hbuf = (u16*)(ws + (32u << 20));        // 16 MiB: ln1-out / av / ln2-out
    u16* big  = (u16*)(ws + (48u << 20));        // 64 MiB: qkv, then ffn act
    u16* qkvb = big;
    u16* ffb  = big;

    dim3 blk(256);

    ln_kernel<<<dim3(B_ * S_), blk, 0, stream>>>(x, ln1_g, ln1_b, hbuf);
    tcvt_kernel<<<dim3(6144 / 32, 2048 / 32), blk, 0, stream>>>(qkv_w, wT, 2048, 6144);
    gemm_kernel<0><<<dim3((6144 / 128) * (4096 / 128)), blk, 0, stream>>>(
        hbuf, wT, qkv_b, nullptr, (void*)qkvb, 4096, 6144, 2048);
    attn_kernel<<<dim3(S_ / 128, B_ * H_), blk, 0, stream>>>(qkvb, hbuf);
    tcvt_kernel<<<dim3(2048 / 32, 2048 / 32), blk, 0, stream>>>(out_w, wT, 2048, 2048);
    gemm_kernel<2><<<dim3((2048 / 128) * (4096 / 128)), blk, 0, stream>>>(
        hbuf, wT, out_b, x, (void*)out, 4096, 2048, 2048);
    ln_kernel<<<dim3(B_ * S_), blk, 0, stream>>>(out, ln2_g, ln2_b, hbuf);
    tcvt_kernel<<<dim3(8192 / 32, 2048 / 32), blk, 0, stream>>>(w1, wT, 2048, 8192);
    gemm_kernel<1><<<dim3((8192 / 128) * (4096 / 128)), blk, 0, stream>>>(
        hbuf, wT, b1, nullptr, (void*)ffb, 4096, 8192, 2048);
    tcvt_kernel<<<dim3(2048 / 32, 8192 / 32), blk, 0, stream>>>(w2, wT, 8192, 2048);
    gemm_kernel<2><<<dim3((2048 / 128) * (4096 / 128)), blk, 0, stream>>>(
        ffb, wT, b2, out, (void*)out, 4096, 2048, 8192);
}